// Round 3
// baseline (174.787 us; speedup 1.0000x reference)
//
#include <hip/hip_runtime.h>
#include <math.h>

// Problem constants (from reference):
//   B=8, R=50 (rafs has 2R=100 channels), C=150, H=W=128, N=4096, K=192
#define KPTS   192
#define RDIM   50
#define BDIM   8
#define HDIM   128
#define WDIM   128
#define NREL   4096
#define CDIM   150
#define LOSS_W 0.1f
#define WPB    4                           // waves (relations) per block
#define BLK    (WPB * 64)
#define PLANE  (HDIM * WDIM)
#define NBLOCKS (NREL / WPB)               // 1024 — all co-resident (4 blocks/CU)
#define RAF_F4  (BDIM * 2 * RDIM * PLANE / 4)   // 3,276,800 float4 in rafs (52 MB)
#define PF_PER_BLOCK (RAF_F4 / NBLOCKS)    // 3200 float4 per block (52 KB)

// Fused single kernel:
//  Phase 0: cooperative L3-warm — each of the 1024 co-resident blocks streams
//           a contiguous 52 KB slice of rafs (coalesced float4, keep-alive asm).
//           The poison fill evicts L3 every iteration; this refills it at
//           streaming BW so the scattered sample gathers below become L3 hits
//           instead of stride-512B HBM misses.
//  Phase 1/2: per-relation sampling — INSTRUCTION-IDENTICAL to the verified
//           round-1 kernel (absmax=0): branchless clamp-gather, shfl-up dup
//           check, wave64 shuffle reduction.
//  Finish:  fence+ticket "last block reduces" — same deterministic summation
//           order as the old reduce_kernel, saves one launch.
__global__ __launch_bounds__(BLK) void relation_fused_kernel(
    const float* __restrict__ rafs,      // (B, 2R, H, W)
    const float* __restrict__ heatmaps,  // (B, C, H, W)
    const int*   __restrict__ rels,      // (N, 8)
    float* __restrict__ ws,              // [0,NREL): partials; [NREL]: int ticket (pre-zeroed)
    float* __restrict__ out)             // scalar loss
{
    const int tid  = threadIdx.x;
    const int wave = tid >> 6;
    const int lane = tid & 63;
    const int rel  = blockIdx.x * WPB + wave;

    // Per-relation header: two 16B loads, broadcast to SGPRs. These cold
    // misses (and the two heatmap loads) resolve under the prefetch stream.
    const int4* r4 = (const int4*)(rels + (size_t)rel * 8);
    const int4 ra = r4[0];   // bi, scls, sy, sx
    const int4 rb = r4[1];   // ocls, oy, ox, pred
    const int bi   = __builtin_amdgcn_readfirstlane(ra.x);
    const int scls = __builtin_amdgcn_readfirstlane(ra.y);
    const int sy   = __builtin_amdgcn_readfirstlane(ra.z);
    const int sx   = __builtin_amdgcn_readfirstlane(ra.w);
    const int ocls = __builtin_amdgcn_readfirstlane(rb.x);
    const int oy   = __builtin_amdgcn_readfirstlane(rb.y);
    const int ox   = __builtin_amdgcn_readfirstlane(rb.z);
    const int pred = __builtin_amdgcn_readfirstlane(rb.w);

    const float subj = heatmaps[(((size_t)bi * CDIM + (size_t)scls) * HDIM + (size_t)sy) * WDIM + (size_t)sx];
    const float obj  = heatmaps[(((size_t)bi * CDIM + (size_t)ocls) * HDIM + (size_t)oy) * WDIM + (size_t)ox];

    const float dx = (float)(ox - sx);
    const float dy = (float)(oy - sy);
    const float norms = sqrtf(dx * dx + dy * dy);
    const float ux = dx / norms;
    const float uy = dy / norms;
    const int   num = (int)ceilf(norms);           // 1..180 < 192
    const float denom = (float)((num - 1) > 1 ? (num - 1) : 1);

    const float oxf = (float)ox, oyf = (float)oy;
    const float sxmox = (float)(sx - ox);
    const float symoy = (float)(sy - oy);

    const size_t rafbase =
        ((size_t)bi * (2 * RDIM) + (size_t)(2 * pred)) * (size_t)PLANE;

    // ---- Phase 0: cooperative L3 warm of rafs (reads only; values kept
    // alive through empty asm so the loads can't be DCE'd — rule #17).
    {
        const float4* __restrict__ src = (const float4*)rafs;
        const int base = blockIdx.x * PF_PER_BLOCK;
        float kx = 0.f, ky = 0.f, kz = 0.f, kw = 0.f;
        for (int i = tid; i < PF_PER_BLOCK; i += BLK) {
            const float4 v = src[base + i];
            kx += v.x; ky += v.y; kz += v.z; kw += v.w;
        }
        asm volatile("" :: "v"(kx), "v"(ky), "v"(kz), "v"(kw));
    }

    // ---- Phase 1: all sample points, all gathers issued branchlessly.
    int   pxs[3], pys[3];
    float vxs[3], vys[3];
    #pragma unroll
    for (int s = 0; s < 3; ++s) {
        const int k  = lane + 64 * s;
        const int kk = (k < num) ? k : (num - 1);       // clamp: safe addr, same line
        const float t  = (float)kk / denom;             // EXACT reference expression
        const int   px = (int)rintf(oxf + t * sxmox);
        const int   py = (int)rintf(oyf + t * symoy);
        pxs[s] = px;
        pys[s] = py;
        const size_t off = (size_t)py * WDIM + (size_t)px;
        vxs[s] = rafs[rafbase + off];
        vys[s] = rafs[rafbase + (size_t)PLANE + off];
    }

    // ---- Phase 2: masked accumulate; neighbor lane supplies the bitwise-
    // exact previous px/py for the dup check.
    float dot  = 0.0f;
    int   vcnt = 0;
    int   px63 = -1, py63 = -1;
    #pragma unroll
    for (int s = 0; s < 3; ++s) {
        int pxp = __shfl_up(pxs[s], 1, 64);
        int pyp = __shfl_up(pys[s], 1, 64);
        if (lane == 0) { pxp = px63; pyp = py63; }
        px63 = __shfl(pxs[s], 63, 64);
        py63 = __shfl(pys[s], 63, 64);

        const int  k   = lane + 64 * s;
        const bool dup = (pxs[s] == pxp) && (pys[s] == pyp);
        if ((k < num) && !dup) {
            float vx = fminf(fmaxf(vxs[s], -1.0f), 1.0f);
            float vy = fminf(fmaxf(vys[s], -1.0f), 1.0f);
            dot  += vx * ux + vy * uy;
            vcnt += 1;
        }
    }

    // Wave64 shuffle reduction.
    #pragma unroll
    for (int off = 32; off > 0; off >>= 1) {
        dot  += __shfl_down(dot,  off, 64);
        vcnt += __shfl_down(vcnt, off, 64);
    }

    if (lane == 0) {
        float integral = dot / (float)vcnt;          // vcnt >= 1 (k=0 always valid)
        integral = fminf(fmaxf(integral, 0.0f), 1.0f);
        const float rs = subj * obj * integral;
        ws[rel] = logf(fmaxf(rs, 1e-12f));
    }

    // ---- Finish: last arriving block does the (order-fixed, deterministic)
    // final reduction. Canonical fence+ticket pattern:
    //   writers: stores -> __syncthreads (vmcnt drained) -> release fence ->
    //            atomic ticket; reader: sees last ticket -> acquire fence ->
    //            reads all partials.
    __shared__ int amLast;
    __syncthreads();
    if (tid == 0) {
        __threadfence();                              // release: flush this XCD's L2
        int* cnt = (int*)(ws + NREL);                 // pre-zeroed via hipMemsetAsync
        const int old = atomicAdd(cnt, 1);            // device-scope
        amLast = (old == NBLOCKS - 1) ? 1 : 0;
        if (amLast) __threadfence();                  // acquire: invalidate before reads
    }
    __syncthreads();

    if (amLast) {
        float acc = 0.0f;
        #pragma unroll
        for (int j = 0; j < NREL / BLK; ++j)          // identical order to old reduce_kernel
            acc += ws[tid + j * BLK];

        #pragma unroll
        for (int off = 32; off > 0; off >>= 1)
            acc += __shfl_down(acc, off, 64);

        __shared__ float s[WPB];
        if (lane == 0) s[wave] = acc;
        __syncthreads();
        if (tid == 0) {
            const float total = s[0] + s[1] + s[2] + s[3];
            out[0] = total * (-LOSS_W / (float)NREL);
        }
    }
}

extern "C" void kernel_launch(void* const* d_in, const int* in_sizes, int n_in,
                              void* d_out, int out_size, void* d_ws, size_t ws_size,
                              hipStream_t stream) {
    const float* rafs     = (const float*)d_in[0];
    const float* heatmaps = (const float*)d_in[1];
    const int*   rels     = (const int*)d_in[2];
    float*       out      = (float*)d_out;
    float*       part     = (float*)d_ws;

    // Zero the 4-byte ticket counter (workspace is poisoned before every
    // iteration). hipMemsetAsync is graph-capturable.
    hipMemsetAsync((void*)(part + NREL), 0, sizeof(int), stream);

    relation_fused_kernel<<<NBLOCKS, BLK, 0, stream>>>(rafs, heatmaps, rels, part, out);
}